// Round 3
// baseline (621.517 us; speedup 1.0000x reference)
//
#include <hip/hip_runtime.h>
#include <hip/hip_bf16.h>
#include <stdint.h>

// CrossAttention: B=4 T=2048 HIN=1024 H=16 E=64
// cvt(X->bf16, scratch=d_out) + Wt transpose -> all-bf16 proj GEMM (async LDS both operands,
// XCD-aware grid) -> flash attn (S^T=K*Q^T so P is A-fragment-native; raw v_exp_f32;
// LOG2E folded into Q's stored scale).
// This round: attn LDS ELIMINATED (1-wave blocks have zero LDS reuse -- it was a pure
// layout shim; K/V MFMA fragments now loaded direct from global, coalesced + L2-resident),
// q-per-wave halved to 32 -> grid 4096 = 16 blocks/CU = 4 waves/SIMD so other waves'
// VALU/exp overlaps MFMA (MFMA blocks its issuing wave on CDNA4 -- overlap is cross-wave).

typedef __bf16 bf16;
typedef __attribute__((ext_vector_type(8))) __bf16 bf16x8;
typedef __attribute__((ext_vector_type(4))) __bf16 bf16x4;
typedef __attribute__((ext_vector_type(4))) float f32x4;
typedef __attribute__((ext_vector_type(4))) short s16x4;

#define B_    4
#define T_    2048
#define HIN_  1024
#define H_    16
#define E_    64
#define NOUT_ 1024
#define LOG2E 1.4426950408889634f
#define QKSCALE 0.35355339059327373f   // 64^(-0.25)
#define QSCALE  (QKSCALE * LOG2E)      // fold log2(e) into Q so p = exp2(S) directly

__device__ __forceinline__ void gl_lds16(const void* g, void* l) {
  __builtin_amdgcn_global_load_lds((__attribute__((address_space(1))) void*)g,
                                   (__attribute__((address_space(3))) void*)l,
                                   16, 0, 0);
}

// ---- X fp32 -> bf16 ----
__global__ __launch_bounds__(256) void cvt_kernel(const float* __restrict__ Xq,
                                                  const float* __restrict__ Xkv,
                                                  bf16* __restrict__ Xb) {
  const float* src = blockIdx.y ? Xkv : Xq;
  bf16* dst = Xb + (size_t)blockIdx.y * (8192 * 1024);
  size_t i = ((size_t)blockIdx.x * 256 + threadIdx.x) * 8;
  float4 f0 = ((const float4*)(src + i))[0];
  float4 f1 = ((const float4*)(src + i))[1];
  bf16x8 t = {(bf16)f0.x, (bf16)f0.y, (bf16)f0.z, (bf16)f0.w,
              (bf16)f1.x, (bf16)f1.y, (bf16)f1.z, (bf16)f1.w};
  *(bf16x8*)(dst + i) = t;
}

// ---- W transpose + fp32->bf16: Wt[z][n][k] = W_z[k][n] ----
__global__ __launch_bounds__(256) void wt_kernel(const float* __restrict__ Wq,
                                                 const float* __restrict__ Wk,
                                                 const float* __restrict__ Wv,
                                                 bf16* __restrict__ Wt) {
  __shared__ float s[32][33];
  const int z = blockIdx.z;
  const float* W = (z == 0) ? Wq : ((z == 1) ? Wk : Wv);
  bf16* out = Wt + (size_t)z * HIN_ * NOUT_;
  const int n0 = blockIdx.x * 32, k0 = blockIdx.y * 32;
  const int tx = threadIdx.x, ty = threadIdx.y;
#pragma unroll
  for (int i = 0; i < 4; i++)
    s[ty + i * 8][tx] = W[(size_t)(k0 + ty + i * 8) * NOUT_ + n0 + tx];
  __syncthreads();
#pragma unroll
  for (int i = 0; i < 4; i++)
    out[(size_t)(n0 + ty + i * 8) * HIN_ + k0 + tx] = (bf16)s[tx][ty + i * 8];
}

// ---- QKV projection, all-bf16, 128x128 tile, BK=64 ----
// grid (64, 8, 3). z<2: mt=bx (XCD=mt%8 -> A-tiles L2-resident), nt=by.
// z=2: nt=bx (XCD=nt%8 -> Xkv-tiles L2-resident), mt=by.
__global__ __launch_bounds__(256, 4) void proj_kernel(const bf16* __restrict__ Xb,
                                                      const bf16* __restrict__ Wt,
                                                      bf16* __restrict__ Qb,
                                                      bf16* __restrict__ Kb,
                                                      bf16* __restrict__ Vtb) {
  __shared__ bf16 As[128 * 64];
  __shared__ bf16 Bs[128 * 64];
  const int z = blockIdx.z;
  const bf16* Abase = (z == 0) ? Xb : ((z == 1) ? Xb + (size_t)8192 * 1024 : Wt + (size_t)2 * HIN_ * NOUT_);
  const bf16* Bbase = (z == 0) ? Wt : ((z == 1) ? Wt + (size_t)HIN_ * NOUT_ : Xb + (size_t)8192 * 1024);
  const int mt = (z == 2) ? blockIdx.y : blockIdx.x;
  const int nt = (z == 2) ? blockIdx.x : blockIdx.y;
  const int m0 = mt * 128, n0 = nt * 128;
  const int tid = threadIdx.x;
  const int w = tid >> 6, lane = tid & 63, quad = lane >> 4, lo = lane & 15;
  const int wm = (w >> 1) * 64, wn = (w & 1) * 64;
  const int srow = w * 8 + (lane >> 3);
  const int schunk = (lane & 7) ^ (srow & 7);

  f32x4 acc[4][4] = {};

  for (int k0 = 0; k0 < HIN_; k0 += 64) {
    __syncthreads();
#pragma unroll
    for (int j = 0; j < 4; j++) {
      int row = j * 32 + srow;
      gl_lds16(Abase + (size_t)(m0 + row) * HIN_ + k0 + schunk * 8, As + (j * 32 + w * 8) * 64);
      gl_lds16(Bbase + (size_t)(n0 + row) * HIN_ + k0 + schunk * 8, Bs + (j * 32 + w * 8) * 64);
    }
    __syncthreads();
#pragma unroll
    for (int kk = 0; kk < 2; kk++) {
      bf16x8 bfrag[4], afrag[4];
#pragma unroll
      for (int j = 0; j < 4; j++) {
        int off = ((((kk << 2) + quad) ^ (lo & 7)) << 3);
        bfrag[j] = *(const bf16x8*)(Bs + (wn + j * 16 + lo) * 64 + off);
        afrag[j] = *(const bf16x8*)(As + (wm + j * 16 + lo) * 64 + off);
      }
#pragma unroll
      for (int i = 0; i < 4; i++)
#pragma unroll
        for (int j = 0; j < 4; j++)
          acc[i][j] = __builtin_amdgcn_mfma_f32_16x16x32_bf16(afrag[i], bfrag[j], acc[i][j], 0, 0, 0);
    }
  }

#pragma unroll
  for (int i = 0; i < 4; i++)
#pragma unroll
    for (int j = 0; j < 4; j++)
#pragma unroll
      for (int r = 0; r < 4; r++) {
        int m = m0 + wm + i * 16 + quad * 4 + r;
        int n = n0 + wn + j * 16 + lo;
        float v = acc[i][j][r];
        if (z == 2) {
          int h = m >> 6, e = m & 63, b = n >> 11, t = n & 2047;
          Vtb[(((size_t)b * H_ + h) * E_ + e) * T_ + t] = (bf16)v;
        } else {
          int b = m >> 11, t = m & 2047, h = n >> 6, e = n & 63;
          if (z == 0)
            Qb[(((size_t)b * H_ + h) * T_ + t) * E_ + e] = (bf16)(v * QSCALE);
          else
            Kb[(((size_t)b * H_ + h) * T_ + t) * E_ + e] = (bf16)(v * QKSCALE);
        }
      }
}

// ---- Flash attention: 1-wave blocks, 32 q/wave, 64-key tiles, NO LDS ----
// K/V fragments loaded directly from global (L2-resident; K: 16B/lane over 64B-contig
// rows, V: 8B/lane over 32B-contig rows). grid (qblocks, bh) so consecutive blocks
// share a bh's K/V in L1/L2. 4 waves/SIMD -> cross-wave MFMA/VALU overlap.
__global__ __launch_bounds__(64, 4) void attn_kernel(const bf16* __restrict__ Qb,
                                                     const bf16* __restrict__ Kb,
                                                     const bf16* __restrict__ Vtb,
                                                     float* __restrict__ out) {
  const int lane = threadIdx.x & 63;
  const int quad = lane >> 4, lo = lane & 15;
  const int bh = blockIdx.y, q0 = blockIdx.x * 32;
  const bf16* Qg = Qb + (size_t)bh * T_ * E_;
  const bf16* Kg = Kb + (size_t)bh * T_ * E_;
  const bf16* Vg = Vtb + (size_t)bh * E_ * T_;

  // Q fragments in registers (B-operand: n=lo -> q, k=quad*8+j -> e)
  bf16x8 qf[2][2];
#pragma unroll
  for (int qi = 0; qi < 2; qi++)
#pragma unroll
    for (int ks = 0; ks < 2; ks++)
      qf[qi][ks] = *(const bf16x8*)(Qg + (size_t)(q0 + qi * 16 + lo) * E_ + ks * 32 + quad * 8);

  f32x4 acc[2][4] = {};
  float lsum[2] = {0.f, 0.f};

  for (int kt = 0; kt < T_ / 64; kt++) {
    // K fragments direct from global (A-operand: m=lo -> t, k=quad*8+j -> e)
    bf16x8 kf[4][2];
#pragma unroll
    for (int ti = 0; ti < 4; ti++)
#pragma unroll
      for (int ks = 0; ks < 2; ks++)
        kf[ti][ks] = *(const bf16x8*)(Kg + (size_t)(kt * 64 + ti * 16 + lo) * E_ + ks * 32 + quad * 8);

    // S^T tiles + exp2 -> P fragments (A-layout for 16x16x16)
    bf16x4 pf[2][4];
#pragma unroll
    for (int qi = 0; qi < 2; qi++) {
      f32x4 st[4] = {};
#pragma unroll
      for (int ks = 0; ks < 2; ks++)
#pragma unroll
        for (int ti = 0; ti < 4; ti++)
          st[ti] = __builtin_amdgcn_mfma_f32_16x16x32_bf16(kf[ti][ks], qf[qi][ks], st[ti], 0, 0, 0);
      float ls = 0.f;
#pragma unroll
      for (int ti = 0; ti < 4; ti++) {
        bf16x4 p4;
#pragma unroll
        for (int r = 0; r < 4; r++) {
          float p = __builtin_amdgcn_exp2f(st[ti][r]);  // raw v_exp_f32
          ls += p;
          p4[r] = (bf16)p;
        }
        pf[qi][ti] = p4;
      }
      lsum[qi] += ls;
    }

    // O += P @ V via 16x16x16 (B-operand: n=lo -> e, k=quad*4+j -> t)
    // V fragment direct from global: row e = ej*16+lo, cols t = kt*64 + tc*16 + quad*4
#pragma unroll
    for (int tc = 0; tc < 4; tc++)
#pragma unroll
      for (int ej = 0; ej < 4; ej++) {
        bf16x4 vf = *(const bf16x4*)(Vg + (size_t)(ej * 16 + lo) * T_ + kt * 64 + tc * 16 + quad * 4);
#pragma unroll
        for (int qi = 0; qi < 2; qi++)
          acc[qi][ej] = __builtin_amdgcn_mfma_f32_16x16x16bf16_1k(
              __builtin_bit_cast(s16x4, pf[qi][tc]), __builtin_bit_cast(s16x4, vf),
              acc[qi][ej], 0, 0, 0);
      }
  }

  const int b = bh >> 4, h = bh & 15;
#pragma unroll
  for (int qi = 0; qi < 2; qi++) {
    float l = lsum[qi];
    l += __shfl_xor(l, 16);
    l += __shfl_xor(l, 32);  // all quads hold full sum for q = qi*16+lo
#pragma unroll
    for (int r = 0; r < 4; r++) {
      float linv = __builtin_amdgcn_rcpf(__shfl(l, quad * 4 + r));
      size_t t = q0 + qi * 16 + quad * 4 + r;
#pragma unroll
      for (int ej = 0; ej < 4; ej++)
        out[((size_t)b * T_ + t) * NOUT_ + h * E_ + ej * 16 + lo] = acc[qi][ej][r] * linv;
    }
  }
}

extern "C" void kernel_launch(void* const* d_in, const int* in_sizes, int n_in,
                              void* d_out, int out_size, void* d_ws, size_t ws_size,
                              hipStream_t stream) {
  const float* Xq  = (const float*)d_in[0];
  const float* Xkv = (const float*)d_in[1];
  const float* Wq  = (const float*)d_in[2];
  const float* Wk  = (const float*)d_in[3];
  const float* Wv  = (const float*)d_in[4];
  float* out = (float*)d_out;

  char* ws = (char*)d_ws;
  bf16* Qb  = (bf16*)(ws);                        // 16 MB [B][H][T][E]
  bf16* Kb  = (bf16*)(ws + ((size_t)16 << 20));   // 16 MB [B][H][T][E]
  bf16* Vtb = (bf16*)(ws + ((size_t)32 << 20));   // 16 MB [B][H][E][T]
  bf16* Wt  = (bf16*)(ws + ((size_t)48 << 20));   // 6 MB  3 x [N][K]
  bf16* Xb  = (bf16*)d_out;                       // 32 MB scratch (d_out unread until attn)

  hipLaunchKernelGGL(cvt_kernel, dim3(4096, 2), dim3(256), 0, stream, Xq, Xkv, Xb);
  hipLaunchKernelGGL(wt_kernel, dim3(32, 32, 3), dim3(32, 8), 0, stream, Wq, Wk, Wv, Wt);
  hipLaunchKernelGGL(proj_kernel, dim3(64, 8, 3), dim3(256), 0, stream, Xb, Wt, Qb, Kb, Vtb);
  hipLaunchKernelGGL(attn_kernel, dim3(64, 64), dim3(64), 0, stream, Qb, Kb, Vtb, out);
}

// Round 4
// 319.064 us; speedup vs baseline: 1.9479x; 1.9479x over previous
//
#include <hip/hip_runtime.h>
#include <hip/hip_bf16.h>
#include <stdint.h>

// CrossAttention: B=4 T=2048 HIN=1024 H=16 E=64
// cvt(X->bf16, scratch=d_out) + Wt transpose -> all-bf16 proj GEMM (async LDS both operands,
// XCD-aware grid) -> flash attn (S^T=K*Q^T so P is A-fragment-native; raw v_exp_f32;
// LOG2E folded into Q's stored scale).
// This round: round-2 attn structure (1-wave blocks, gl_lds staging, wave-local vmcnt(0),
// no barriers) with the work slice halved: KVBLK=32, 32 q/wave -> ~80 VGPR, 8KB LDS,
// grid 4096 = 16 blocks/CU = 4 waves/SIMD (2x round-2 residency) to interleave the
// serial QK->exp->PV latency chains across waves. Total work unchanged, sliced finer.

typedef __bf16 bf16;
typedef __attribute__((ext_vector_type(8))) __bf16 bf16x8;
typedef __attribute__((ext_vector_type(4))) __bf16 bf16x4;
typedef __attribute__((ext_vector_type(4))) float f32x4;
typedef __attribute__((ext_vector_type(4))) short s16x4;

#define B_    4
#define T_    2048
#define HIN_  1024
#define H_    16
#define E_    64
#define NOUT_ 1024
#define LOG2E 1.4426950408889634f
#define QKSCALE 0.35355339059327373f   // 64^(-0.25)
#define QSCALE  (QKSCALE * LOG2E)      // fold log2(e) into Q so p = exp2(S) directly

__device__ __forceinline__ void gl_lds16(const void* g, void* l) {
  __builtin_amdgcn_global_load_lds((__attribute__((address_space(1))) void*)g,
                                   (__attribute__((address_space(3))) void*)l,
                                   16, 0, 0);
}

// ---- X fp32 -> bf16 ----
__global__ __launch_bounds__(256) void cvt_kernel(const float* __restrict__ Xq,
                                                  const float* __restrict__ Xkv,
                                                  bf16* __restrict__ Xb) {
  const float* src = blockIdx.y ? Xkv : Xq;
  bf16* dst = Xb + (size_t)blockIdx.y * (8192 * 1024);
  size_t i = ((size_t)blockIdx.x * 256 + threadIdx.x) * 8;
  float4 f0 = ((const float4*)(src + i))[0];
  float4 f1 = ((const float4*)(src + i))[1];
  bf16x8 t = {(bf16)f0.x, (bf16)f0.y, (bf16)f0.z, (bf16)f0.w,
              (bf16)f1.x, (bf16)f1.y, (bf16)f1.z, (bf16)f1.w};
  *(bf16x8*)(dst + i) = t;
}

// ---- W transpose + fp32->bf16: Wt[z][n][k] = W_z[k][n] ----
__global__ __launch_bounds__(256) void wt_kernel(const float* __restrict__ Wq,
                                                 const float* __restrict__ Wk,
                                                 const float* __restrict__ Wv,
                                                 bf16* __restrict__ Wt) {
  __shared__ float s[32][33];
  const int z = blockIdx.z;
  const float* W = (z == 0) ? Wq : ((z == 1) ? Wk : Wv);
  bf16* out = Wt + (size_t)z * HIN_ * NOUT_;
  const int n0 = blockIdx.x * 32, k0 = blockIdx.y * 32;
  const int tx = threadIdx.x, ty = threadIdx.y;
#pragma unroll
  for (int i = 0; i < 4; i++)
    s[ty + i * 8][tx] = W[(size_t)(k0 + ty + i * 8) * NOUT_ + n0 + tx];
  __syncthreads();
#pragma unroll
  for (int i = 0; i < 4; i++)
    out[(size_t)(n0 + ty + i * 8) * HIN_ + k0 + tx] = (bf16)s[tx][ty + i * 8];
}

// ---- QKV projection, all-bf16, 128x128 tile, BK=64 ----
// grid (64, 8, 3). z<2: mt=bx (XCD=mt%8 -> A-tiles L2-resident), nt=by.
// z=2: nt=bx (XCD=nt%8 -> Xkv-tiles L2-resident), mt=by.
__global__ __launch_bounds__(256, 4) void proj_kernel(const bf16* __restrict__ Xb,
                                                      const bf16* __restrict__ Wt,
                                                      bf16* __restrict__ Qb,
                                                      bf16* __restrict__ Kb,
                                                      bf16* __restrict__ Vtb) {
  __shared__ bf16 As[128 * 64];
  __shared__ bf16 Bs[128 * 64];
  const int z = blockIdx.z;
  const bf16* Abase = (z == 0) ? Xb : ((z == 1) ? Xb + (size_t)8192 * 1024 : Wt + (size_t)2 * HIN_ * NOUT_);
  const bf16* Bbase = (z == 0) ? Wt : ((z == 1) ? Wt + (size_t)HIN_ * NOUT_ : Xb + (size_t)8192 * 1024);
  const int mt = (z == 2) ? blockIdx.y : blockIdx.x;
  const int nt = (z == 2) ? blockIdx.x : blockIdx.y;
  const int m0 = mt * 128, n0 = nt * 128;
  const int tid = threadIdx.x;
  const int w = tid >> 6, lane = tid & 63, quad = lane >> 4, lo = lane & 15;
  const int wm = (w >> 1) * 64, wn = (w & 1) * 64;
  const int srow = w * 8 + (lane >> 3);
  const int schunk = (lane & 7) ^ (srow & 7);

  f32x4 acc[4][4] = {};

  for (int k0 = 0; k0 < HIN_; k0 += 64) {
    __syncthreads();
#pragma unroll
    for (int j = 0; j < 4; j++) {
      int row = j * 32 + srow;
      gl_lds16(Abase + (size_t)(m0 + row) * HIN_ + k0 + schunk * 8, As + (j * 32 + w * 8) * 64);
      gl_lds16(Bbase + (size_t)(n0 + row) * HIN_ + k0 + schunk * 8, Bs + (j * 32 + w * 8) * 64);
    }
    __syncthreads();
#pragma unroll
    for (int kk = 0; kk < 2; kk++) {
      bf16x8 bfrag[4], afrag[4];
#pragma unroll
      for (int j = 0; j < 4; j++) {
        int off = ((((kk << 2) + quad) ^ (lo & 7)) << 3);
        bfrag[j] = *(const bf16x8*)(Bs + (wn + j * 16 + lo) * 64 + off);
        afrag[j] = *(const bf16x8*)(As + (wm + j * 16 + lo) * 64 + off);
      }
#pragma unroll
      for (int i = 0; i < 4; i++)
#pragma unroll
        for (int j = 0; j < 4; j++)
          acc[i][j] = __builtin_amdgcn_mfma_f32_16x16x32_bf16(afrag[i], bfrag[j], acc[i][j], 0, 0, 0);
    }
  }

#pragma unroll
  for (int i = 0; i < 4; i++)
#pragma unroll
    for (int j = 0; j < 4; j++)
#pragma unroll
      for (int r = 0; r < 4; r++) {
        int m = m0 + wm + i * 16 + quad * 4 + r;
        int n = n0 + wn + j * 16 + lo;
        float v = acc[i][j][r];
        if (z == 2) {
          int h = m >> 6, e = m & 63, b = n >> 11, t = n & 2047;
          Vtb[(((size_t)b * H_ + h) * E_ + e) * T_ + t] = (bf16)v;
        } else {
          int b = m >> 11, t = m & 2047, h = n >> 6, e = n & 63;
          if (z == 0)
            Qb[(((size_t)b * H_ + h) * T_ + t) * E_ + e] = (bf16)(v * QSCALE);
          else
            Kb[(((size_t)b * H_ + h) * T_ + t) * E_ + e] = (bf16)(v * QKSCALE);
        }
      }
}

// ---- Flash attention: 1-wave blocks, 32 q/wave, 32-key tiles, NO barriers ----
// Wave-private K/V staging via global_load_lds; wave-local s_waitcnt vmcnt(0).
// 8KB LDS/block, ~80 VGPR -> 16 blocks/CU = 4 waves/SIMD for cross-wave latency hiding.
__global__ __launch_bounds__(64, 4) void attn_kernel(const bf16* __restrict__ Qb,
                                                     const bf16* __restrict__ Kb,
                                                     const bf16* __restrict__ Vtb,
                                                     float* __restrict__ out) {
  __shared__ bf16 Ks[32 * 64];   // [t'][e] 32 rows x 128B, chunk-XOR swizzled
  __shared__ bf16 Vts[64 * 32];  // [e][t'] 64 rows x 64B,  chunk-XOR swizzled
  const int lane = threadIdx.x & 63;
  const int quad = lane >> 4, lo = lane & 15;
  const int bh = blockIdx.y, q0 = blockIdx.x * 32;
  const bf16* Qg = Qb + (size_t)bh * T_ * E_;
  const bf16* Kg = Kb + (size_t)bh * T_ * E_;
  const bf16* Vg = Vtb + (size_t)bh * E_ * T_;
  // K staging: 8 rows/instr of 128B; stored[r][c] = src[r][c^(r&7)], c in 16B chunks
  const int srowK = lane >> 3;                   // 0..7
  const int schunkK = (lane & 7) ^ srowK;        // XOR'd source chunk (r&7 == srowK)
  // V staging: 16 rows/instr of 64B; stored[r][c] = src[r][c^(r&3)], c in 16B chunks
  const int srowV = lane >> 2;                   // 0..15
  const int schunkV = (lane & 3) ^ (srowV & 3);  // XOR'd source chunk

  // Q fragments in registers (B-operand: n=lo -> q, k=quad*8+j -> e)
  bf16x8 qf[2][2];
#pragma unroll
  for (int qi = 0; qi < 2; qi++)
#pragma unroll
    for (int ks = 0; ks < 2; ks++)
      qf[qi][ks] = *(const bf16x8*)(Qg + (size_t)(q0 + qi * 16 + lo) * E_ + ks * 32 + quad * 8);

  f32x4 acc[2][4] = {};
  float lsum[2] = {0.f, 0.f};

  for (int kt = 0; kt < T_ / 32; kt++) {
    // stage K tile (32 t-rows x 64 e) and V tile (64 e-rows x 32 t): 4 insts each
#pragma unroll
    for (int i = 0; i < 4; i++) {
      gl_lds16(Kg + (size_t)(kt * 32 + i * 8 + srowK) * E_ + schunkK * 8,
               Ks + (i * 8) * 64);
      gl_lds16(Vg + (size_t)(i * 16 + srowV) * T_ + kt * 32 + schunkV * 8,
               Vts + (i * 16) * 32);
    }
    asm volatile("s_waitcnt vmcnt(0)" ::: "memory");  // wave-local: tile resident
    __builtin_amdgcn_sched_barrier(0);                 // pin ds_reads below the wait

    // K fragments (A-operand: m=lo -> t, k=quad*8+j -> e)
    bf16x8 kf[2][2];
#pragma unroll
    for (int ti = 0; ti < 2; ti++)
#pragma unroll
      for (int ks = 0; ks < 2; ks++)
        kf[ti][ks] = *(const bf16x8*)(Ks + (ti * 16 + lo) * 64 + ((((ks << 2) + quad) ^ (lo & 7)) << 3));

    // S^T tiles + exp2 -> P fragments (A-layout for 16x16x16)
    bf16x4 pf[2][2];
#pragma unroll
    for (int qi = 0; qi < 2; qi++) {
      f32x4 st[2] = {};
#pragma unroll
      for (int ks = 0; ks < 2; ks++)
#pragma unroll
        for (int ti = 0; ti < 2; ti++)
          st[ti] = __builtin_amdgcn_mfma_f32_16x16x32_bf16(kf[ti][ks], qf[qi][ks], st[ti], 0, 0, 0);
      float ls = 0.f;
#pragma unroll
      for (int ti = 0; ti < 2; ti++) {
        bf16x4 p4;
#pragma unroll
        for (int r = 0; r < 4; r++) {
          float p = __builtin_amdgcn_exp2f(st[ti][r]);  // raw v_exp_f32
          ls += p;
          p4[r] = (bf16)p;
        }
        pf[qi][ti] = p4;
      }
      lsum[qi] += ls;
    }

    // O += P @ V via 16x16x16 (B-operand: n=lo -> e, k=quad*4+j -> t)
    // V read: row e=ej*16+lo, src chunk cs = tc*2 + (quad>>1) -> stored chunk cs^(lo&3)
#pragma unroll
    for (int tc = 0; tc < 2; tc++)
#pragma unroll
      for (int ej = 0; ej < 4; ej++) {
        bf16x4 vf = *(const bf16x4*)(Vts + (ej * 16 + lo) * 32 +
                                     (((tc * 2 + (quad >> 1)) ^ (lo & 3)) << 3) + (quad & 1) * 4);
#pragma unroll
        for (int qi = 0; qi < 2; qi++)
          acc[qi][ej] = __builtin_amdgcn_mfma_f32_16x16x16bf16_1k(
              __builtin_bit_cast(s16x4, pf[qi][tc]), __builtin_bit_cast(s16x4, vf),
              acc[qi][ej], 0, 0, 0);
      }
  }

  const int b = bh >> 4, h = bh & 15;
#pragma unroll
  for (int qi = 0; qi < 2; qi++) {
    float l = lsum[qi];
    l += __shfl_xor(l, 16);
    l += __shfl_xor(l, 32);  // all quads hold full sum for q = qi*16+lo
#pragma unroll
    for (int r = 0; r < 4; r++) {
      float linv = __builtin_amdgcn_rcpf(__shfl(l, quad * 4 + r));
      size_t t = q0 + qi * 16 + quad * 4 + r;
#pragma unroll
      for (int ej = 0; ej < 4; ej++)
        out[((size_t)b * T_ + t) * NOUT_ + h * E_ + ej * 16 + lo] = acc[qi][ej][r] * linv;
    }
  }
}

extern "C" void kernel_launch(void* const* d_in, const int* in_sizes, int n_in,
                              void* d_out, int out_size, void* d_ws, size_t ws_size,
                              hipStream_t stream) {
  const float* Xq  = (const float*)d_in[0];
  const float* Xkv = (const float*)d_in[1];
  const float* Wq  = (const float*)d_in[2];
  const float* Wk  = (const float*)d_in[3];
  const float* Wv  = (const float*)d_in[4];
  float* out = (float*)d_out;

  char* ws = (char*)d_ws;
  bf16* Qb  = (bf16*)(ws);                        // 16 MB [B][H][T][E]
  bf16* Kb  = (bf16*)(ws + ((size_t)16 << 20));   // 16 MB [B][H][T][E]
  bf16* Vtb = (bf16*)(ws + ((size_t)32 << 20));   // 16 MB [B][H][E][T]
  bf16* Wt  = (bf16*)(ws + ((size_t)48 << 20));   // 6 MB  3 x [N][K]
  bf16* Xb  = (bf16*)d_out;                       // 32 MB scratch (d_out unread until attn)

  hipLaunchKernelGGL(cvt_kernel, dim3(4096, 2), dim3(256), 0, stream, Xq, Xkv, Xb);
  hipLaunchKernelGGL(wt_kernel, dim3(32, 32, 3), dim3(32, 8), 0, stream, Wq, Wk, Wv, Wt);
  hipLaunchKernelGGL(proj_kernel, dim3(64, 8, 3), dim3(256), 0, stream, Xb, Wt, Qb, Kb, Vtb);
  hipLaunchKernelGGL(attn_kernel, dim3(64, 64), dim3(64), 0, stream, Qb, Kb, Vtb, out);
}

// Round 6
// 242.757 us; speedup vs baseline: 2.5602x; 1.3143x over previous
//
#include <hip/hip_runtime.h>
#include <hip/hip_bf16.h>
#include <stdint.h>

// CrossAttention: B=4 T=2048 HIN=1024 H=16 E=64
// cvt(X->bf16, scratch=d_out) + Wt transpose -> all-bf16 proj GEMM (async LDS both operands,
// XCD-aware grid) -> flash attn.
// Round 5 resubmit (infra failure last round): attn on 32x32x16 MFMA for BOTH GEMMs
// (halves MFMA issue cycles vs 16x16 shapes; PV was on half-efficiency 16x16x16_1k).
// P redistribution from QK C-layout to PV A-layout via v_cvt_pk_bf16_f32 (inline asm,
// no builtin) + __builtin_amdgcn_permlane32_swap (vdst.hi <-> src.lo). Round-2 shell:
// 1-wave blocks, 64 q/wave, KVBLK=64, XOR-swizzled 128B-row LDS tiles, wave-local
// vmcnt(0), no barriers.

typedef __bf16 bf16;
typedef __attribute__((ext_vector_type(8))) __bf16 bf16x8;
typedef __attribute__((ext_vector_type(4))) float f32x4;
typedef __attribute__((ext_vector_type(16))) float f32x16;
typedef __attribute__((ext_vector_type(4))) unsigned int u32x4;
typedef __attribute__((ext_vector_type(2))) unsigned int u32x2;

#define B_    4
#define T_    2048
#define HIN_  1024
#define H_    16
#define E_    64
#define NOUT_ 1024
#define LOG2E 1.4426950408889634f
#define QKSCALE 0.35355339059327373f   // 64^(-0.25)
#define QSCALE  (QKSCALE * LOG2E)      // fold log2(e) into Q so p = exp2(S) directly

__device__ __forceinline__ void gl_lds16(const void* g, void* l) {
  __builtin_amdgcn_global_load_lds((__attribute__((address_space(1))) void*)g,
                                   (__attribute__((address_space(3))) void*)l,
                                   16, 0, 0);
}

// ---- X fp32 -> bf16 ----
__global__ __launch_bounds__(256) void cvt_kernel(const float* __restrict__ Xq,
                                                  const float* __restrict__ Xkv,
                                                  bf16* __restrict__ Xb) {
  const float* src = blockIdx.y ? Xkv : Xq;
  bf16* dst = Xb + (size_t)blockIdx.y * (8192 * 1024);
  size_t i = ((size_t)blockIdx.x * 256 + threadIdx.x) * 8;
  float4 f0 = ((const float4*)(src + i))[0];
  float4 f1 = ((const float4*)(src + i))[1];
  bf16x8 t = {(bf16)f0.x, (bf16)f0.y, (bf16)f0.z, (bf16)f0.w,
              (bf16)f1.x, (bf16)f1.y, (bf16)f1.z, (bf16)f1.w};
  *(bf16x8*)(dst + i) = t;
}

// ---- W transpose + fp32->bf16: Wt[z][n][k] = W_z[k][n] ----
__global__ __launch_bounds__(256) void wt_kernel(const float* __restrict__ Wq,
                                                 const float* __restrict__ Wk,
                                                 const float* __restrict__ Wv,
                                                 bf16* __restrict__ Wt) {
  __shared__ float s[32][33];
  const int z = blockIdx.z;
  const float* W = (z == 0) ? Wq : ((z == 1) ? Wk : Wv);
  bf16* out = Wt + (size_t)z * HIN_ * NOUT_;
  const int n0 = blockIdx.x * 32, k0 = blockIdx.y * 32;
  const int tx = threadIdx.x, ty = threadIdx.y;
#pragma unroll
  for (int i = 0; i < 4; i++)
    s[ty + i * 8][tx] = W[(size_t)(k0 + ty + i * 8) * NOUT_ + n0 + tx];
  __syncthreads();
#pragma unroll
  for (int i = 0; i < 4; i++)
    out[(size_t)(n0 + ty + i * 8) * HIN_ + k0 + tx] = (bf16)s[tx][ty + i * 8];
}

// ---- QKV projection, all-bf16, 128x128 tile, BK=64 ----
__global__ __launch_bounds__(256, 4) void proj_kernel(const bf16* __restrict__ Xb,
                                                      const bf16* __restrict__ Wt,
                                                      bf16* __restrict__ Qb,
                                                      bf16* __restrict__ Kb,
                                                      bf16* __restrict__ Vtb) {
  __shared__ bf16 As[128 * 64];
  __shared__ bf16 Bs[128 * 64];
  const int z = blockIdx.z;
  const bf16* Abase = (z == 0) ? Xb : ((z == 1) ? Xb + (size_t)8192 * 1024 : Wt + (size_t)2 * HIN_ * NOUT_);
  const bf16* Bbase = (z == 0) ? Wt : ((z == 1) ? Wt + (size_t)HIN_ * NOUT_ : Xb + (size_t)8192 * 1024);
  const int mt = (z == 2) ? blockIdx.y : blockIdx.x;
  const int nt = (z == 2) ? blockIdx.x : blockIdx.y;
  const int m0 = mt * 128, n0 = nt * 128;
  const int tid = threadIdx.x;
  const int w = tid >> 6, lane = tid & 63, quad = lane >> 4, lo = lane & 15;
  const int wm = (w >> 1) * 64, wn = (w & 1) * 64;
  const int srow = w * 8 + (lane >> 3);
  const int schunk = (lane & 7) ^ (srow & 7);

  f32x4 acc[4][4] = {};

  for (int k0 = 0; k0 < HIN_; k0 += 64) {
    __syncthreads();
#pragma unroll
    for (int j = 0; j < 4; j++) {
      int row = j * 32 + srow;
      gl_lds16(Abase + (size_t)(m0 + row) * HIN_ + k0 + schunk * 8, As + (j * 32 + w * 8) * 64);
      gl_lds16(Bbase + (size_t)(n0 + row) * HIN_ + k0 + schunk * 8, Bs + (j * 32 + w * 8) * 64);
    }
    __syncthreads();
#pragma unroll
    for (int kk = 0; kk < 2; kk++) {
      bf16x8 bfrag[4], afrag[4];
#pragma unroll
      for (int j = 0; j < 4; j++) {
        int off = ((((kk << 2) + quad) ^ (lo & 7)) << 3);
        bfrag[j] = *(const bf16x8*)(Bs + (wn + j * 16 + lo) * 64 + off);
        afrag[j] = *(const bf16x8*)(As + (wm + j * 16 + lo) * 64 + off);
      }
#pragma unroll
      for (int i = 0; i < 4; i++)
#pragma unroll
        for (int j = 0; j < 4; j++)
          acc[i][j] = __builtin_amdgcn_mfma_f32_16x16x32_bf16(afrag[i], bfrag[j], acc[i][j], 0, 0, 0);
    }
  }

#pragma unroll
  for (int i = 0; i < 4; i++)
#pragma unroll
    for (int j = 0; j < 4; j++)
#pragma unroll
      for (int r = 0; r < 4; r++) {
        int m = m0 + wm + i * 16 + quad * 4 + r;
        int n = n0 + wn + j * 16 + lo;
        float v = acc[i][j][r];
        if (z == 2) {
          int h = m >> 6, e = m & 63, b = n >> 11, t = n & 2047;
          Vtb[(((size_t)b * H_ + h) * E_ + e) * T_ + t] = (bf16)v;
        } else {
          int b = m >> 11, t = m & 2047, h = n >> 6, e = n & 63;
          if (z == 0)
            Qb[(((size_t)b * H_ + h) * T_ + t) * E_ + e] = (bf16)(v * QSCALE);
          else
            Kb[(((size_t)b * H_ + h) * T_ + t) * E_ + e] = (bf16)(v * QKSCALE);
        }
      }
}

// ---- Flash attention: 1-wave blocks, 64 q/wave, 64-key tiles, 32x32x16 MFMA ----
// QK: A=K(m=t), B=Q(n=q) -> lane holds q=l31, t over 16 regs (t=(r&3)+8(r>>2)+4hi).
// P->PV-A: cvt_pk pairs + permlane32_swap (new_a={a.lo,b.lo} -> j0..3 words,
// new_b={a.hi,b.hi} -> j4..7 words). PV: A=P(m=q,k=t), B=V^T(n=e,k=t).
__global__ __launch_bounds__(64, 2) void attn_kernel(const bf16* __restrict__ Qb,
                                                     const bf16* __restrict__ Kb,
                                                     const bf16* __restrict__ Vtb,
                                                     float* __restrict__ out) {
  __shared__ bf16 Ks[64 * 64];   // [t'][e] rows 128B, chunk c stored at c^(row&7)
  __shared__ bf16 Vts[64 * 64];  // [e][t'] rows 128B, same swizzle
  const int lane = threadIdx.x & 63;
  const int l31 = lane & 31, hi = lane >> 5;
  const int bh = blockIdx.x, q0 = blockIdx.y * 64;
  const bf16* Qg = Qb + (size_t)bh * T_ * E_;
  const bf16* Kg = Kb + (size_t)bh * T_ * E_;
  const bf16* Vg = Vtb + (size_t)bh * E_ * T_;
  const int srow = lane >> 3;                 // 0..7 within 8-row staging group
  const int schunk = (lane & 7) ^ (srow & 7); // XOR'd source chunk

  // Q fragments (B-operand: n=l31 -> q, k=hi*8+j -> e), 4 k-steps of 16
  bf16x8 qf[2][4];
#pragma unroll
  for (int qb = 0; qb < 2; qb++)
#pragma unroll
    for (int ks = 0; ks < 4; ks++)
      qf[qb][ks] = *(const bf16x8*)(Qg + (size_t)(q0 + qb * 32 + l31) * E_ + ks * 16 + hi * 8);

  f32x16 acc[2][2] = {};
  float lsum[2] = {0.f, 0.f};

  for (int kt = 0; kt < T_ / 64; kt++) {
    // stage K tile [64t'][64e] and V tile [64e][64t']: 8 gl_lds each
#pragma unroll
    for (int i = 0; i < 8; i++) {
      int row = i * 8 + srow;
      gl_lds16(Kg + (size_t)(kt * 64 + row) * E_ + schunk * 8, Ks + (i * 8) * 64);
      gl_lds16(Vg + (size_t)row * T_ + kt * 64 + schunk * 8, Vts + (i * 8) * 64);
    }
    asm volatile("s_waitcnt vmcnt(0)" ::: "memory");  // wave-local: tile resident
    __builtin_amdgcn_sched_barrier(0);                 // pin ds_reads below the wait

    // K fragments (A-operand: m=l31 -> t, k=hi*8+j -> e)
    bf16x8 kf[2][4];
#pragma unroll
    for (int tb = 0; tb < 2; tb++)
#pragma unroll
      for (int ks = 0; ks < 4; ks++)
        kf[tb][ks] = *(const bf16x8*)(Ks + (tb * 32 + l31) * 64 +
                                      (((2 * ks + hi) ^ (l31 & 7)) << 3));

    // QK -> exp2 -> packed P A-fragments
    bf16x8 pf[2][4];  // [qb][tc16]
#pragma unroll
    for (int qb = 0; qb < 2; qb++) {
#pragma unroll
      for (int tb = 0; tb < 2; tb++) {
        f32x16 st = {};
#pragma unroll
        for (int ks = 0; ks < 4; ks++)
          st = __builtin_amdgcn_mfma_f32_32x32x16_bf16(kf[tb][ks], qf[qb][ks], st, 0, 0, 0);
        // lane holds S[q = qb*32+l31][t'' = tb*32 + (r&3)+8*(r>>2)+4*hi]
        float ex[16];
        float ls = 0.f;
#pragma unroll
        for (int r = 0; r < 16; r++) {
          ex[r] = __builtin_amdgcn_exp2f(st[r]);
          ls += ex[r];
        }
        lsum[qb] += ls;
        // pack pairs: u[g][p] covers t'' = tb*32 + 8g + 4*hi + 2p + {0,1}
        unsigned int u[4][2];
#pragma unroll
        for (int g = 0; g < 4; g++)
#pragma unroll
          for (int p = 0; p < 2; p++)
            asm("v_cvt_pk_bf16_f32 %0, %1, %2"
                : "=v"(u[g][p]) : "v"(ex[4 * g + 2 * p]), "v"(ex[4 * g + 2 * p + 1]));
        // redistribute: swap(u[2c2][p], u[2c2+1][p]) -> frag tc16 = tb*2+c2:
        // new_vdst holds j = 2p+{0,1} (words 0,1), new_src holds j = 4+2p+{0,1} (words 2,3)
#pragma unroll
        for (int c2 = 0; c2 < 2; c2++) {
          u32x2 s0 = __builtin_amdgcn_permlane32_swap(u[2 * c2][0], u[2 * c2 + 1][0], false, false);
          u32x2 s1 = __builtin_amdgcn_permlane32_swap(u[2 * c2][1], u[2 * c2 + 1][1], false, false);
          u32x4 wv = {s0[0], s1[0], s0[1], s1[1]};
          pf[qb][tb * 2 + c2] = __builtin_bit_cast(bf16x8, wv);
        }
      }
    }

    // O += P @ V (A=P: m=l31->q, k=hi*8+j->t ; B=V^T: n=l31->e, k=hi*8+j->t)
#pragma unroll
    for (int tc = 0; tc < 4; tc++)
#pragma unroll
      for (int eb = 0; eb < 2; eb++) {
        bf16x8 vf = *(const bf16x8*)(Vts + (eb * 32 + l31) * 64 +
                                     (((2 * tc + hi) ^ (l31 & 7)) << 3));
#pragma unroll
        for (int qb = 0; qb < 2; qb++)
          acc[qb][eb] = __builtin_amdgcn_mfma_f32_32x32x16_bf16(pf[qb][tc], vf, acc[qb][eb], 0, 0, 0);
      }
  }

  // lane's regs covered half the t's; other half in lane^32
#pragma unroll
  for (int qb = 0; qb < 2; qb++)
    lsum[qb] += __shfl_xor(lsum[qb], 32);  // full sum for q = qb*32 + l31

  const int b = bh >> 4, h = bh & 15;
#pragma unroll
  for (int qb = 0; qb < 2; qb++)
#pragma unroll
    for (int r = 0; r < 16; r++) {
      int qrow = (r & 3) + 8 * (r >> 2) + 4 * hi;  // 0..31
      float linv = __builtin_amdgcn_rcpf(__shfl(lsum[qb], qrow));
      size_t t = q0 + qb * 32 + qrow;
#pragma unroll
      for (int eb = 0; eb < 2; eb++)
        out[((size_t)b * T_ + t) * NOUT_ + h * E_ + eb * 32 + l31] = acc[qb][eb][r] * linv;
    }
}

extern "C" void kernel_launch(void* const* d_in, const int* in_sizes, int n_in,
                              void* d_out, int out_size, void* d_ws, size_t ws_size,
                              hipStream_t stream) {
  const float* Xq  = (const float*)d_in[0];
  const float* Xkv = (const float*)d_in[1];
  const float* Wq  = (const float*)d_in[2];
  const float* Wk  = (const float*)d_in[3];
  const float* Wv  = (const float*)d_in[4];
  float* out = (float*)d_out;

  char* ws = (char*)d_ws;
  bf16* Qb  = (bf16*)(ws);                        // 16 MB [B][H][T][E]
  bf16* Kb  = (bf16*)(ws + ((size_t)16 << 20));   // 16 MB [B][H][T][E]
  bf16* Vtb = (bf16*)(ws + ((size_t)32 << 20));   // 16 MB [B][H][E][T]
  bf16* Wt  = (bf16*)(ws + ((size_t)48 << 20));   // 6 MB  3 x [N][K]
  bf16* Xb  = (bf16*)d_out;                       // 32 MB scratch (d_out unread until attn)

  hipLaunchKernelGGL(cvt_kernel, dim3(4096, 2), dim3(256), 0, stream, Xq, Xkv, Xb);
  hipLaunchKernelGGL(wt_kernel, dim3(32, 32, 3), dim3(32, 8), 0, stream, Wq, Wk, Wv, Wt);
  hipLaunchKernelGGL(proj_kernel, dim3(64, 8, 3), dim3(256), 0, stream, Xb, Wt, Qb, Kb, Vtb);
  hipLaunchKernelGGL(attn_kernel, dim3(64, 32), dim3(64), 0, stream, Qb, Kb, Vtb, out);
}